// Round 10
// baseline (328.446 us; speedup 1.0000x reference)
//
#include <hip/hip_runtime.h>

#define BB 32768
#define FF 16
#define HH 64
#define OO 32
#define EE 16

typedef float v2f __attribute__((ext_vector_type(2)));

__device__ __forceinline__ v2f pkfma(v2f a, v2f b, v2f c) {
    return __builtin_elementwise_fma(a, b, c);   // -> v_pk_fma_f32
}

// ---------------- Phase 1: per-feature subnets -> tok [B][F][E] ----------------
// Round-9 proven structure (f = blockIdx.y -> uniform weights via s_load, pk_fma).
// Round-10 change: 2 batches/thread (each s_load serves 2x FMAs) + k-chunking
// (2 x 32) to keep the live set ~110 floats. launch_bounds(256,3) -> VGPR
// budget ~170, no spill. Weights stay SGPR (uniform) -- round 6's chunking
// failed only because its weights were divergent/VGPR.
__global__ __launch_bounds__(256, 3) void spinn_subnet_kernel(
    const float* __restrict__ x,
    const float* __restrict__ W1, const float* __restrict__ b1,
    const float* __restrict__ W2, const float* __restrict__ b2,
    const float* __restrict__ W3, const float* __restrict__ b3,
    const float* __restrict__ Wp, const float* __restrict__ bp,
    float* __restrict__ tok)
{
    const int f  = blockIdx.y;
    const int t  = threadIdx.x;
    const int ba = blockIdx.x * 512 + t;        // batch A
    const int bb = ba + 256;                    // batch B

    const float* __restrict__ w1  = W1 + f*HH;      // [64]
    const float* __restrict__ bb1 = b1 + f*HH;
    const float* __restrict__ w2  = W2 + f*HH*HH;   // [64][64]
    const float* __restrict__ bb2 = b2 + f*HH;
    const float* __restrict__ w3  = W3 + f*HH*OO;   // [64][32]
    const float* __restrict__ bb3 = b3 + f*OO;

    const float xva = x[(size_t)ba*FF + f];
    const float xvb = x[(size_t)bb*FF + f];

    // layer-3 accumulators for both batches
    v2f to2a[OO/2], to2b[OO/2];
    #pragma unroll
    for (int o = 0; o < OO/2; ++o) { to2a[o] = *(const v2f*)(bb3 + 2*o); to2b[o] = to2a[o]; }

    // ---- layers 1+2+3, k-chunked (2 x 32 h-units) ----
    #pragma unroll
    for (int c = 0; c < 2; ++c) {
        const int k0 = c*32;
        v2f hca[16], hcb[16];
        #pragma unroll
        for (int k = 0; k < 16; ++k) { hca[k] = *(const v2f*)(bb2 + k0 + 2*k); hcb[k] = hca[k]; }

        #pragma unroll 2
        for (int j = 0; j < HH; ++j) {
            float h1a = fmaf(xva, w1[j], bb1[j]);
            h1a = (h1a >= 0.f) ? h1a : 0.01f*h1a;
            float h1b = fmaf(xvb, w1[j], bb1[j]);
            h1b = (h1b >= 0.f) ? h1b : 0.01f*h1b;
            v2f da; da[0] = h1a; da[1] = h1a;
            v2f db; db[0] = h1b; db[1] = h1b;
            const v2f* wr = (const v2f*)(w2 + j*HH + k0);   // uniform -> s_load
            #pragma unroll
            for (int k = 0; k < 16; ++k) {
                hca[k] = pkfma(da, wr[k], hca[k]);
                hcb[k] = pkfma(db, wr[k], hcb[k]);
            }
        }

        // leaky + fold this chunk into layer 3 (static indexing throughout)
        #pragma unroll
        for (int k = 0; k < 32; ++k) {
            float hva = hca[k>>1][k&1];
            hva = (hva >= 0.f) ? hva : 0.01f*hva;
            float hvb = hcb[k>>1][k&1];
            hvb = (hvb >= 0.f) ? hvb : 0.01f*hvb;
            v2f da; da[0] = hva; da[1] = hva;
            v2f db; db[0] = hvb; db[1] = hvb;
            const v2f* wr3 = (const v2f*)(w3 + (k0 + k)*OO);
            #pragma unroll
            for (int o = 0; o < OO/2; ++o) {
                to2a[o] = pkfma(da, wr3[o], to2a[o]);
                to2b[o] = pkfma(db, wr3[o], to2b[o]);
            }
        }
    }

    // ---- proj O->E for both batches ----
    v2f tea[EE/2], teb[EE/2];
    #pragma unroll
    for (int e = 0; e < EE/2; ++e) { tea[e] = *(const v2f*)(bp + 2*e); teb[e] = tea[e]; }
    #pragma unroll
    for (int o = 0; o < OO; ++o) {
        float ova = to2a[o>>1][o&1];
        float ovb = to2b[o>>1][o&1];
        v2f da; da[0] = ova; da[1] = ova;
        v2f db; db[0] = ovb; db[1] = ovb;
        const v2f* wr = (const v2f*)(Wp + o*EE);
        #pragma unroll
        for (int e = 0; e < EE/2; ++e) {
            tea[e] = pkfma(da, wr[e], tea[e]);
            teb[e] = pkfma(db, wr[e], teb[e]);
        }
    }

    // tok layout [B][F][E]
    float4* dsta = (float4*)(tok + ((size_t)ba*FF + (size_t)f)*EE);
    dsta[0] = make_float4(tea[0][0], tea[0][1], tea[1][0], tea[1][1]);
    dsta[1] = make_float4(tea[2][0], tea[2][1], tea[3][0], tea[3][1]);
    dsta[2] = make_float4(tea[4][0], tea[4][1], tea[5][0], tea[5][1]);
    dsta[3] = make_float4(tea[6][0], tea[6][1], tea[7][0], tea[7][1]);
    float4* dstb = (float4*)(tok + ((size_t)bb*FF + (size_t)f)*EE);
    dstb[0] = make_float4(teb[0][0], teb[0][1], teb[1][0], teb[1][1]);
    dstb[1] = make_float4(teb[2][0], teb[2][1], teb[3][0], teb[3][1]);
    dstb[2] = make_float4(teb[4][0], teb[4][1], teb[5][0], teb[5][1]);
    dstb[3] = make_float4(teb[6][0], teb[6][1], teb[7][0], teb[7][1]);
}

// ---------------- Phase 2: qkv + attention + pool + final FC ----------------
// UNCHANGED from round 9.
#define KVPAD 260   // floats per batch row: 256 + 4 pad

// Full-rate DPP butterfly sum over each aligned 16-lane group (replicated).
__device__ __forceinline__ float sum16(float v) {
    int i;
    i = __builtin_amdgcn_update_dpp(0, __float_as_int(v), 0xB1,  0xF, 0xF, true); v += __int_as_float(i); // xor 1
    i = __builtin_amdgcn_update_dpp(0, __float_as_int(v), 0x4E,  0xF, 0xF, true); v += __int_as_float(i); // xor 2
    i = __builtin_amdgcn_update_dpp(0, __float_as_int(v), 0x141, 0xF, 0xF, true); v += __int_as_float(i); // half-mirror
    i = __builtin_amdgcn_update_dpp(0, __float_as_int(v), 0x140, 0xF, 0xF, true); v += __int_as_float(i); // row mirror
    return v;
}

__global__ __launch_bounds__(256, 4) void spinn_attn_kernel(
    const float* __restrict__ tok,
    const float* __restrict__ Wqkv, const float* __restrict__ bqkv,
    const float* __restrict__ Wo,   const float* __restrict__ bo,
    const float* __restrict__ Wf,   const float* __restrict__ bf,
    float* __restrict__ out)
{
    __shared__ __align__(16) float kb[16*KVPAD];
    __shared__ __align__(16) float vb[16*KVPAD];

    const int t  = threadIdx.x;
    const int f  = t & 15;        // token index (16-lane group)
    const int bl = t >> 4;        // local batch 0..15
    const int gb = blockIdx.x * 16 + bl;

    float tokv[EE];
    {
        const float4* tp = (const float4*)(tok + ((size_t)gb*FF + (size_t)f)*EE);
        float4 v0 = tp[0], v1 = tp[1], v2 = tp[2], v3 = tp[3];
        tokv[0]=v0.x; tokv[1]=v0.y; tokv[2]=v0.z; tokv[3]=v0.w;
        tokv[4]=v1.x; tokv[5]=v1.y; tokv[6]=v1.z; tokv[7]=v1.w;
        tokv[8]=v2.x; tokv[9]=v2.y; tokv[10]=v2.z; tokv[11]=v2.w;
        tokv[12]=v3.x; tokv[13]=v3.y; tokv[14]=v3.z; tokv[15]=v3.w;
    }

    // ---- pass A: q (kept in regs) + k (-> LDS)
    float q[EE], kx[EE];
    #pragma unroll
    for (int i = 0; i < EE; ++i) { q[i] = bqkv[i]; kx[i] = bqkv[EE + i]; }
    #pragma unroll
    for (int e = 0; e < EE; ++e) {
        const float tv = tokv[e];
        #pragma unroll
        for (int i = 0; i < EE; ++i) {
            q[i]  = fmaf(tv, Wqkv[e*48 + i],      q[i]);
            kx[i] = fmaf(tv, Wqkv[e*48 + EE + i], kx[i]);
        }
    }
    {
        float4* kr = (float4*)(kb + bl*KVPAD + f*16);
        kr[0] = make_float4(kx[0],  kx[1],  kx[2],  kx[3]);
        kr[1] = make_float4(kx[4],  kx[5],  kx[6],  kx[7]);
        kr[2] = make_float4(kx[8],  kx[9],  kx[10], kx[11]);
        kr[3] = make_float4(kx[12], kx[13], kx[14], kx[15]);
    }

    // ---- pass B: v (-> LDS)
    {
        float vx[EE];
        #pragma unroll
        for (int i = 0; i < EE; ++i) vx[i] = bqkv[2*EE + i];
        #pragma unroll
        for (int e = 0; e < EE; ++e) {
            const float tv = tokv[e];
            #pragma unroll
            for (int i = 0; i < EE; ++i)
                vx[i] = fmaf(tv, Wqkv[e*48 + 2*EE + i], vx[i]);
        }
        float4* vr = (float4*)(vb + bl*KVPAD + f*16);
        vr[0] = make_float4(vx[0],  vx[1],  vx[2],  vx[3]);
        vr[1] = make_float4(vx[4],  vx[5],  vx[6],  vx[7]);
        vr[2] = make_float4(vx[8],  vx[9],  vx[10], vx[11]);
        vr[3] = make_float4(vx[12], vx[13], vx[14], vx[15]);
    }

    // ---- scores: own q row vs all 16 k rows, scale 0.25
    float s[16];
    #pragma unroll
    for (int kk = 0; kk < 16; ++kk) {
        const float4* krow = (const float4*)(kb + bl*KVPAD + kk*16);
        float4 k0 = krow[0], k1 = krow[1], k2 = krow[2], k3 = krow[3];
        float d = q[0]*k0.x  + q[1]*k0.y  + q[2]*k0.z  + q[3]*k0.w
                + q[4]*k1.x  + q[5]*k1.y  + q[6]*k1.z  + q[7]*k1.w
                + q[8]*k2.x  + q[9]*k2.y  + q[10]*k2.z + q[11]*k2.w
                + q[12]*k3.x + q[13]*k3.y + q[14]*k3.z + q[15]*k3.w;
        s[kk] = d * 0.25f;
    }

    // ---- stable softmax
    float m = s[0];
    #pragma unroll
    for (int kk = 1; kk < 16; ++kk) m = fmaxf(m, s[kk]);
    float sum = 0.f;
    #pragma unroll
    for (int kk = 0; kk < 16; ++kk) { s[kk] = __expf(s[kk] - m); sum += s[kk]; }
    const float inv = 1.0f / sum;
    #pragma unroll
    for (int kk = 0; kk < 16; ++kk) s[kk] *= inv;

    // ---- column sums across the 16 token-lanes -> 16*abar (replicated)
    #pragma unroll
    for (int kk = 0; kk < 16; ++kk) s[kk] = sum16(s[kk]);

    // ---- pooled_v[f]
    float pvf = 0.f;
    #pragma unroll
    for (int kk = 0; kk < 16; ++kk)
        pvf = fmaf(s[kk], vb[bl*KVPAD + kk*16 + f], pvf);
    pvf *= 0.0625f;

    // ---- wof[f] = Wo[f][:] . Wf
    float wof;
    {
        const float4* wr = (const float4*)(Wo + f*EE);
        float4 w0 = wr[0], w1 = wr[1], w2 = wr[2], w3 = wr[3];
        wof = w0.x*Wf[0]  + w0.y*Wf[1]  + w0.z*Wf[2]  + w0.w*Wf[3]
            + w1.x*Wf[4]  + w1.y*Wf[5]  + w1.z*Wf[6]  + w1.w*Wf[7]
            + w2.x*Wf[8]  + w2.y*Wf[9]  + w2.z*Wf[10] + w2.w*Wf[11]
            + w3.x*Wf[12] + w3.y*Wf[13] + w3.z*Wf[14] + w3.w*Wf[15];
    }

    float c = fmaf(pvf, wof, bo[f]*Wf[f]);
    c = sum16(c);

    if (f == 0) {
        float r = c + bf[0];
        out[gb] = (r >= 0.f) ? r : 0.01f*r;
    }
}

extern "C" void kernel_launch(void* const* d_in, const int* in_sizes, int n_in,
                              void* d_out, int out_size, void* d_ws, size_t ws_size,
                              hipStream_t stream)
{
    const float* x    = (const float*)d_in[0];
    const float* W1   = (const float*)d_in[1];
    const float* b1   = (const float*)d_in[2];
    const float* W2   = (const float*)d_in[3];
    const float* b2   = (const float*)d_in[4];
    const float* W3   = (const float*)d_in[5];
    const float* b3   = (const float*)d_in[6];
    const float* Wp   = (const float*)d_in[7];
    const float* bp   = (const float*)d_in[8];
    const float* Wqkv = (const float*)d_in[9];
    const float* bqkv = (const float*)d_in[10];
    const float* Wo   = (const float*)d_in[11];
    const float* bo   = (const float*)d_in[12];
    const float* Wf   = (const float*)d_in[13];
    const float* bf   = (const float*)d_in[14];
    float* out = (float*)d_out;
    float* tok = (float*)d_ws;   // [B][F][E] fp32 = 32 MB scratch

    dim3 g1(BB/512, FF);   // 2 batches per thread
    spinn_subnet_kernel<<<g1, 256, 0, stream>>>(x, W1, b1, W2, b2, W3, b3, Wp, bp, tok);
    spinn_attn_kernel<<<BB/16, 256, 0, stream>>>(tok, Wqkv, bqkv, Wo, bo, Wf, bf, out);
}

// Round 11
// 200.229 us; speedup vs baseline: 1.6403x; 1.6403x over previous
//
#include <hip/hip_runtime.h>

#define BB 32768
#define FF 16
#define HH 64
#define OO 32
#define EE 16

typedef float v2f __attribute__((ext_vector_type(2)));

__device__ __forceinline__ v2f pkfma(v2f a, v2f b, v2f c) {
    return __builtin_elementwise_fma(a, b, c);   // -> v_pk_fma_f32
}

// fp32 -> bf16 pair pack (RNE), and bf16 -> fp32 unpack (exact)
__device__ __forceinline__ unsigned bfpack(float lo, float hi) {
    unsigned a = __float_as_uint(lo), b = __float_as_uint(hi);
    a = (a + 0x7FFFu + ((a >> 16) & 1u)) >> 16;
    b = (b + 0x7FFFu + ((b >> 16) & 1u)) >> 16;
    return a | (b << 16);
}
__device__ __forceinline__ float bflo(unsigned u) { return __uint_as_float(u << 16); }
__device__ __forceinline__ float bfhi(unsigned u) { return __uint_as_float(u & 0xFFFF0000u); }

// ---------------- Kernel 0: W3p = W3 @ Wp, bp3 = b3 @ Wp + bp (per feature) ----
__global__ __launch_bounds__(256) void w3p_kernel(
    const float* __restrict__ W3, const float* __restrict__ b3,
    const float* __restrict__ Wp, const float* __restrict__ bp,
    float* __restrict__ w3p, float* __restrict__ bp3)
{
    const int f = blockIdx.x, t = threadIdx.x;
    const float* __restrict__ w3f = W3 + f*HH*OO;
    #pragma unroll
    for (int r = 0; r < 4; ++r) {
        const int idx = t*4 + r;            // 0..1023 -> (j = idx>>4, e = idx&15)
        const int j = idx >> 4, e = idx & 15;
        float acc = 0.f;
        #pragma unroll
        for (int o = 0; o < OO; ++o)
            acc = fmaf(w3f[j*OO + o], Wp[o*EE + e], acc);
        w3p[f*1024 + idx] = acc;
    }
    if (t < EE) {
        float acc = bp[t];
        #pragma unroll
        for (int o = 0; o < OO; ++o)
            acc = fmaf(b3[f*OO + o], Wp[o*EE + t], acc);
        bp3[f*EE + t] = acc;
    }
}

// ---------------- Phase 1: per-feature subnets -> tok(bf16) [B][F][E] ----------
// Round-9 proven shape (f = blockIdx.y -> uniform weights via s_load, pk_fma,
// 1 batch/thread). Round-11: k-chunked (2 x 32) with W3p-folded layer 3 so the
// chunk live set (hc 32 + te 16 floats) fits the ~64-VGPR budget -- no AGPR
// parking, no spill. NEVER raise the live set (rounds 5/6/10: allocator spills).
__global__ __launch_bounds__(256, 4) void spinn_subnet_kernel(
    const float* __restrict__ x,
    const float* __restrict__ W1, const float* __restrict__ b1,
    const float* __restrict__ W2, const float* __restrict__ b2,
    const float* __restrict__ w3p, const float* __restrict__ bp3,
    unsigned* __restrict__ tokb)
{
    const int f = blockIdx.y;
    const int t = threadIdx.x;
    const int b = blockIdx.x * 256 + t;

    const float* __restrict__ w1   = W1  + f*HH;      // [64]
    const float* __restrict__ bb1  = b1  + f*HH;
    const float* __restrict__ w2   = W2  + f*HH*HH;   // [64][64]
    const float* __restrict__ bb2  = b2  + f*HH;
    const float* __restrict__ w3pf = w3p + f*HH*EE;   // [64][16] folded W3@Wp
    const float* __restrict__ bp3f = bp3 + f*EE;

    const float xv = x[(size_t)b*FF + f];

    v2f te[EE/2];                                     // folded layer3+proj acc
    #pragma unroll
    for (int e = 0; e < EE/2; ++e) te[e] = *(const v2f*)(bp3f + 2*e);

    #pragma unroll
    for (int c = 0; c < 2; ++c) {
        const int k0 = c*32;
        v2f hc[16];                                   // h2 chunk [k0, k0+32)
        #pragma unroll
        for (int k = 0; k < 16; ++k) hc[k] = *(const v2f*)(bb2 + k0 + 2*k);

        #pragma unroll 2
        for (int j = 0; j < HH; ++j) {
            float h1 = fmaf(xv, w1[j], bb1[j]);
            h1 = (h1 >= 0.f) ? h1 : 0.01f*h1;
            v2f hd; hd[0] = h1; hd[1] = h1;
            const v2f* wr = (const v2f*)(w2 + j*HH + k0);   // uniform -> s_load
            #pragma unroll
            for (int k = 0; k < 16; ++k)
                hc[k] = pkfma(hd, wr[k], hc[k]);
        }

        // leaky + fold chunk into te via W3p (static indexing throughout)
        #pragma unroll
        for (int k = 0; k < 32; ++k) {
            float hv = hc[k>>1][k&1];
            hv = (hv >= 0.f) ? hv : 0.01f*hv;
            v2f hd; hd[0] = hv; hd[1] = hv;
            const v2f* wr3 = (const v2f*)(w3pf + (k0 + k)*EE);  // uniform -> s_load
            #pragma unroll
            for (int e = 0; e < EE/2; ++e)
                te[e] = pkfma(hd, wr3[e], te[e]);
        }
    }

    // write tok row (bf16, 32 B contiguous)
    unsigned* row = tokb + ((size_t)b*FF + (size_t)f)*(EE/2);
    uint4 p0, p1;
    p0.x = bfpack(te[0][0], te[0][1]); p0.y = bfpack(te[1][0], te[1][1]);
    p0.z = bfpack(te[2][0], te[2][1]); p0.w = bfpack(te[3][0], te[3][1]);
    p1.x = bfpack(te[4][0], te[4][1]); p1.y = bfpack(te[5][0], te[5][1]);
    p1.z = bfpack(te[6][0], te[6][1]); p1.w = bfpack(te[7][0], te[7][1]);
    ((uint4*)row)[0] = p0;
    ((uint4*)row)[1] = p1;
}

// ---------------- Phase 2: qkv + attention + pool + final FC ----------------
// Round-9 structure unchanged except tok is bf16 (half the read bytes).
#define KVPAD 260   // floats per batch row: 256 + 4 pad

__device__ __forceinline__ float sum16(float v) {
    int i;
    i = __builtin_amdgcn_update_dpp(0, __float_as_int(v), 0xB1,  0xF, 0xF, true); v += __int_as_float(i); // xor 1
    i = __builtin_amdgcn_update_dpp(0, __float_as_int(v), 0x4E,  0xF, 0xF, true); v += __int_as_float(i); // xor 2
    i = __builtin_amdgcn_update_dpp(0, __float_as_int(v), 0x141, 0xF, 0xF, true); v += __int_as_float(i); // half-mirror
    i = __builtin_amdgcn_update_dpp(0, __float_as_int(v), 0x140, 0xF, 0xF, true); v += __int_as_float(i); // row mirror
    return v;
}

__global__ __launch_bounds__(256, 4) void spinn_attn_kernel(
    const unsigned* __restrict__ tokb,
    const float* __restrict__ Wqkv, const float* __restrict__ bqkv,
    const float* __restrict__ Wo,   const float* __restrict__ bo,
    const float* __restrict__ Wf,   const float* __restrict__ bf,
    float* __restrict__ out)
{
    __shared__ __align__(16) float kb[16*KVPAD];
    __shared__ __align__(16) float vb[16*KVPAD];

    const int t  = threadIdx.x;
    const int f  = t & 15;        // token index (16-lane group)
    const int bl = t >> 4;        // local batch 0..15
    const int gb = blockIdx.x * 16 + bl;

    float tokv[EE];
    {
        const uint4* tp = (const uint4*)(tokb + ((size_t)gb*FF + (size_t)f)*(EE/2));
        uint4 u0 = tp[0], u1 = tp[1];
        tokv[0]  = bflo(u0.x); tokv[1]  = bfhi(u0.x);
        tokv[2]  = bflo(u0.y); tokv[3]  = bfhi(u0.y);
        tokv[4]  = bflo(u0.z); tokv[5]  = bfhi(u0.z);
        tokv[6]  = bflo(u0.w); tokv[7]  = bfhi(u0.w);
        tokv[8]  = bflo(u1.x); tokv[9]  = bfhi(u1.x);
        tokv[10] = bflo(u1.y); tokv[11] = bfhi(u1.y);
        tokv[12] = bflo(u1.z); tokv[13] = bfhi(u1.z);
        tokv[14] = bflo(u1.w); tokv[15] = bfhi(u1.w);
    }

    // ---- pass A: q (regs) + k (-> LDS)
    float q[EE], kx[EE];
    #pragma unroll
    for (int i = 0; i < EE; ++i) { q[i] = bqkv[i]; kx[i] = bqkv[EE + i]; }
    #pragma unroll
    for (int e = 0; e < EE; ++e) {
        const float tv = tokv[e];
        #pragma unroll
        for (int i = 0; i < EE; ++i) {
            q[i]  = fmaf(tv, Wqkv[e*48 + i],      q[i]);
            kx[i] = fmaf(tv, Wqkv[e*48 + EE + i], kx[i]);
        }
    }
    {
        float4* kr = (float4*)(kb + bl*KVPAD + f*16);
        kr[0] = make_float4(kx[0],  kx[1],  kx[2],  kx[3]);
        kr[1] = make_float4(kx[4],  kx[5],  kx[6],  kx[7]);
        kr[2] = make_float4(kx[8],  kx[9],  kx[10], kx[11]);
        kr[3] = make_float4(kx[12], kx[13], kx[14], kx[15]);
    }

    // ---- pass B: v (-> LDS)
    {
        float vx[EE];
        #pragma unroll
        for (int i = 0; i < EE; ++i) vx[i] = bqkv[2*EE + i];
        #pragma unroll
        for (int e = 0; e < EE; ++e) {
            const float tv = tokv[e];
            #pragma unroll
            for (int i = 0; i < EE; ++i)
                vx[i] = fmaf(tv, Wqkv[e*48 + 2*EE + i], vx[i]);
        }
        float4* vr = (float4*)(vb + bl*KVPAD + f*16);
        vr[0] = make_float4(vx[0],  vx[1],  vx[2],  vx[3]);
        vr[1] = make_float4(vx[4],  vx[5],  vx[6],  vx[7]);
        vr[2] = make_float4(vx[8],  vx[9],  vx[10], vx[11]);
        vr[3] = make_float4(vx[12], vx[13], vx[14], vx[15]);
    }

    // ---- scores vs all 16 k rows, scale 0.25
    float s[16];
    #pragma unroll
    for (int kk = 0; kk < 16; ++kk) {
        const float4* krow = (const float4*)(kb + bl*KVPAD + kk*16);
        float4 k0 = krow[0], k1 = krow[1], k2 = krow[2], k3 = krow[3];
        float d = q[0]*k0.x  + q[1]*k0.y  + q[2]*k0.z  + q[3]*k0.w
                + q[4]*k1.x  + q[5]*k1.y  + q[6]*k1.z  + q[7]*k1.w
                + q[8]*k2.x  + q[9]*k2.y  + q[10]*k2.z + q[11]*k2.w
                + q[12]*k3.x + q[13]*k3.y + q[14]*k3.z + q[15]*k3.w;
        s[kk] = d * 0.25f;
    }

    // ---- stable softmax
    float m = s[0];
    #pragma unroll
    for (int kk = 1; kk < 16; ++kk) m = fmaxf(m, s[kk]);
    float sum = 0.f;
    #pragma unroll
    for (int kk = 0; kk < 16; ++kk) { s[kk] = __expf(s[kk] - m); sum += s[kk]; }
    const float inv = 1.0f / sum;
    #pragma unroll
    for (int kk = 0; kk < 16; ++kk) s[kk] *= inv;

    // ---- column sums across 16 token-lanes -> 16*abar (replicated)
    #pragma unroll
    for (int kk = 0; kk < 16; ++kk) s[kk] = sum16(s[kk]);

    // ---- pooled_v[f]
    float pvf = 0.f;
    #pragma unroll
    for (int kk = 0; kk < 16; ++kk)
        pvf = fmaf(s[kk], vb[bl*KVPAD + kk*16 + f], pvf);
    pvf *= 0.0625f;

    // ---- wof[f] = Wo[f][:] . Wf
    float wof;
    {
        const float4* wr = (const float4*)(Wo + f*EE);
        float4 w0 = wr[0], w1 = wr[1], w2 = wr[2], w3 = wr[3];
        wof = w0.x*Wf[0]  + w0.y*Wf[1]  + w0.z*Wf[2]  + w0.w*Wf[3]
            + w1.x*Wf[4]  + w1.y*Wf[5]  + w1.z*Wf[6]  + w1.w*Wf[7]
            + w2.x*Wf[8]  + w2.y*Wf[9]  + w2.z*Wf[10] + w2.w*Wf[11]
            + w3.x*Wf[12] + w3.y*Wf[13] + w3.z*Wf[14] + w3.w*Wf[15];
    }

    float c = fmaf(pvf, wof, bo[f]*Wf[f]);
    c = sum16(c);

    if (f == 0) {
        float r = c + bf[0];
        out[gb] = (r >= 0.f) ? r : 0.01f*r;
    }
}

extern "C" void kernel_launch(void* const* d_in, const int* in_sizes, int n_in,
                              void* d_out, int out_size, void* d_ws, size_t ws_size,
                              hipStream_t stream)
{
    const float* x    = (const float*)d_in[0];
    const float* W1   = (const float*)d_in[1];
    const float* b1   = (const float*)d_in[2];
    const float* W2   = (const float*)d_in[3];
    const float* b2   = (const float*)d_in[4];
    const float* W3   = (const float*)d_in[5];
    const float* b3   = (const float*)d_in[6];
    const float* Wp   = (const float*)d_in[7];
    const float* bp   = (const float*)d_in[8];
    const float* Wqkv = (const float*)d_in[9];
    const float* bqkv = (const float*)d_in[10];
    const float* Wo   = (const float*)d_in[11];
    const float* bo   = (const float*)d_in[12];
    const float* Wf   = (const float*)d_in[13];
    const float* bf   = (const float*)d_in[14];
    float* out = (float*)d_out;

    // d_ws layout: [0,16MiB) tok bf16 [B][F][E]; at 16MiB: W3p fp32 (64KB) + bp3 (1KB)
    unsigned* tokb = (unsigned*)d_ws;
    float* w3p = (float*)((char*)d_ws + (16u << 20));
    float* bp3 = w3p + FF*HH*EE;

    w3p_kernel<<<FF, 256, 0, stream>>>(W3, b3, Wp, bp, w3p, bp3);
    dim3 g1(BB/256, FF);
    spinn_subnet_kernel<<<g1, 256, 0, stream>>>(x, W1, b1, W2, b2, w3p, bp3, tokb);
    spinn_attn_kernel<<<BB/16, 256, 0, stream>>>(tokb, Wqkv, bqkv, Wo, bo, Wf, bf, out);
}

// Round 12
// 188.345 us; speedup vs baseline: 1.7439x; 1.0631x over previous
//
#include <hip/hip_runtime.h>

#define BB 32768
#define FF 16
#define HH 64
#define OO 32
#define EE 16

typedef float v2f __attribute__((ext_vector_type(2)));

__device__ __forceinline__ v2f pkfma(v2f a, v2f b, v2f c) {
    return __builtin_elementwise_fma(a, b, c);   // -> v_pk_fma_f32
}

// fp32 -> bf16 pair pack (RNE), and bf16 -> fp32 unpack (exact)
__device__ __forceinline__ unsigned bfpack(float lo, float hi) {
    unsigned a = __float_as_uint(lo), b = __float_as_uint(hi);
    a = (a + 0x7FFFu + ((a >> 16) & 1u)) >> 16;
    b = (b + 0x7FFFu + ((b >> 16) & 1u)) >> 16;
    return a | (b << 16);
}
__device__ __forceinline__ float bflo(unsigned u) { return __uint_as_float(u << 16); }
__device__ __forceinline__ float bfhi(unsigned u) { return __uint_as_float(u & 0xFFFF0000u); }

// ---------------- Kernel 0: W3p = W3 @ Wp, bp3 = b3 @ Wp + bp (per feature) ----
__global__ __launch_bounds__(256) void w3p_kernel(
    const float* __restrict__ W3, const float* __restrict__ b3,
    const float* __restrict__ Wp, const float* __restrict__ bp,
    float* __restrict__ w3p, float* __restrict__ bp3)
{
    const int f = blockIdx.x, t = threadIdx.x;
    const float* __restrict__ w3f = W3 + f*HH*OO;
    #pragma unroll
    for (int r = 0; r < 4; ++r) {
        const int idx = t*4 + r;            // 0..1023 -> (j = idx>>4, e = idx&15)
        const int j = idx >> 4, e = idx & 15;
        float acc = 0.f;
        #pragma unroll
        for (int o = 0; o < OO; ++o)
            acc = fmaf(w3f[j*OO + o], Wp[o*EE + e], acc);
        w3p[f*1024 + idx] = acc;
    }
    if (t < EE) {
        float acc = bp[t];
        #pragma unroll
        for (int o = 0; o < OO; ++o)
            acc = fmaf(b3[f*OO + o], Wp[o*EE + t], acc);
        bp3[f*EE + t] = acc;
    }
}

// ---------------- Phase 1: per-feature subnets -> tok(bf16) [B][F][E] ----------
// Round-11 structure (uniform weights via s_load, pk_fma, k-chunked, W3p fold).
// Round-12 single change: 1-D grid + feature/CU co-location remap. Blocks that
// share a CU (linear-id stride 256) now share f = g & 15, so the per-CU scalar
// weight working set is 21 KB (K$-resident) instead of ~8 features x 21 KB
// (K$ thrash -> every s_load at L2 latency -> the 42% VALU stall).
__global__ __launch_bounds__(256, 4) void spinn_subnet_kernel(
    const float* __restrict__ x,
    const float* __restrict__ W1, const float* __restrict__ b1,
    const float* __restrict__ W2, const float* __restrict__ b2,
    const float* __restrict__ w3p, const float* __restrict__ bp3,
    unsigned* __restrict__ tokb)
{
    const int g  = blockIdx.x;
    const int f  = g & 15;                               // same-CU blocks share f
    const int mt = ((g >> 8) << 4) | ((g & 255) >> 4);   // batch tile, bijective
    const int t  = threadIdx.x;
    const int b  = mt * 256 + t;

    const float* __restrict__ w1   = W1  + f*HH;      // [64]
    const float* __restrict__ bb1  = b1  + f*HH;
    const float* __restrict__ w2   = W2  + f*HH*HH;   // [64][64]
    const float* __restrict__ bb2  = b2  + f*HH;
    const float* __restrict__ w3pf = w3p + f*HH*EE;   // [64][16] folded W3@Wp
    const float* __restrict__ bp3f = bp3 + f*EE;

    const float xv = x[(size_t)b*FF + f];

    v2f te[EE/2];                                     // folded layer3+proj acc
    #pragma unroll
    for (int e = 0; e < EE/2; ++e) te[e] = *(const v2f*)(bp3f + 2*e);

    #pragma unroll
    for (int c = 0; c < 2; ++c) {
        const int k0 = c*32;
        v2f hc[16];                                   // h2 chunk [k0, k0+32)
        #pragma unroll
        for (int k = 0; k < 16; ++k) hc[k] = *(const v2f*)(bb2 + k0 + 2*k);

        #pragma unroll 2
        for (int j = 0; j < HH; ++j) {
            float h1 = fmaf(xv, w1[j], bb1[j]);
            h1 = (h1 >= 0.f) ? h1 : 0.01f*h1;
            v2f hd; hd[0] = h1; hd[1] = h1;
            const v2f* wr = (const v2f*)(w2 + j*HH + k0);   // uniform -> s_load
            #pragma unroll
            for (int k = 0; k < 16; ++k)
                hc[k] = pkfma(hd, wr[k], hc[k]);
        }

        // leaky + fold chunk into te via W3p (static indexing throughout)
        #pragma unroll
        for (int k = 0; k < 32; ++k) {
            float hv = hc[k>>1][k&1];
            hv = (hv >= 0.f) ? hv : 0.01f*hv;
            v2f hd; hd[0] = hv; hd[1] = hv;
            const v2f* wr3 = (const v2f*)(w3pf + (k0 + k)*EE);  // uniform -> s_load
            #pragma unroll
            for (int e = 0; e < EE/2; ++e)
                te[e] = pkfma(hd, wr3[e], te[e]);
        }
    }

    // write tok row (bf16, 32 B contiguous)
    unsigned* row = tokb + ((size_t)b*FF + (size_t)f)*(EE/2);
    uint4 p0, p1;
    p0.x = bfpack(te[0][0], te[0][1]); p0.y = bfpack(te[1][0], te[1][1]);
    p0.z = bfpack(te[2][0], te[2][1]); p0.w = bfpack(te[3][0], te[3][1]);
    p1.x = bfpack(te[4][0], te[4][1]); p1.y = bfpack(te[5][0], te[5][1]);
    p1.z = bfpack(te[6][0], te[6][1]); p1.w = bfpack(te[7][0], te[7][1]);
    ((uint4*)row)[0] = p0;
    ((uint4*)row)[1] = p1;
}

// ---------------- Phase 2: qkv + attention + pool + final FC ----------------
// UNCHANGED from round 11.
#define KVPAD 260   // floats per batch row: 256 + 4 pad

__device__ __forceinline__ float sum16(float v) {
    int i;
    i = __builtin_amdgcn_update_dpp(0, __float_as_int(v), 0xB1,  0xF, 0xF, true); v += __int_as_float(i); // xor 1
    i = __builtin_amdgcn_update_dpp(0, __float_as_int(v), 0x4E,  0xF, 0xF, true); v += __int_as_float(i); // xor 2
    i = __builtin_amdgcn_update_dpp(0, __float_as_int(v), 0x141, 0xF, 0xF, true); v += __int_as_float(i); // half-mirror
    i = __builtin_amdgcn_update_dpp(0, __float_as_int(v), 0x140, 0xF, 0xF, true); v += __int_as_float(i); // row mirror
    return v;
}

__global__ __launch_bounds__(256, 4) void spinn_attn_kernel(
    const unsigned* __restrict__ tokb,
    const float* __restrict__ Wqkv, const float* __restrict__ bqkv,
    const float* __restrict__ Wo,   const float* __restrict__ bo,
    const float* __restrict__ Wf,   const float* __restrict__ bf,
    float* __restrict__ out)
{
    __shared__ __align__(16) float kb[16*KVPAD];
    __shared__ __align__(16) float vb[16*KVPAD];

    const int t  = threadIdx.x;
    const int f  = t & 15;        // token index (16-lane group)
    const int bl = t >> 4;        // local batch 0..15
    const int gb = blockIdx.x * 16 + bl;

    float tokv[EE];
    {
        const uint4* tp = (const uint4*)(tokb + ((size_t)gb*FF + (size_t)f)*(EE/2));
        uint4 u0 = tp[0], u1 = tp[1];
        tokv[0]  = bflo(u0.x); tokv[1]  = bfhi(u0.x);
        tokv[2]  = bflo(u0.y); tokv[3]  = bfhi(u0.y);
        tokv[4]  = bflo(u0.z); tokv[5]  = bfhi(u0.z);
        tokv[6]  = bflo(u0.w); tokv[7]  = bfhi(u0.w);
        tokv[8]  = bflo(u1.x); tokv[9]  = bfhi(u1.x);
        tokv[10] = bflo(u1.y); tokv[11] = bfhi(u1.y);
        tokv[12] = bflo(u1.z); tokv[13] = bfhi(u1.z);
        tokv[14] = bflo(u1.w); tokv[15] = bfhi(u1.w);
    }

    // ---- pass A: q (regs) + k (-> LDS)
    float q[EE], kx[EE];
    #pragma unroll
    for (int i = 0; i < EE; ++i) { q[i] = bqkv[i]; kx[i] = bqkv[EE + i]; }
    #pragma unroll
    for (int e = 0; e < EE; ++e) {
        const float tv = tokv[e];
        #pragma unroll
        for (int i = 0; i < EE; ++i) {
            q[i]  = fmaf(tv, Wqkv[e*48 + i],      q[i]);
            kx[i] = fmaf(tv, Wqkv[e*48 + EE + i], kx[i]);
        }
    }
    {
        float4* kr = (float4*)(kb + bl*KVPAD + f*16);
        kr[0] = make_float4(kx[0],  kx[1],  kx[2],  kx[3]);
        kr[1] = make_float4(kx[4],  kx[5],  kx[6],  kx[7]);
        kr[2] = make_float4(kx[8],  kx[9],  kx[10], kx[11]);
        kr[3] = make_float4(kx[12], kx[13], kx[14], kx[15]);
    }

    // ---- pass B: v (-> LDS)
    {
        float vx[EE];
        #pragma unroll
        for (int i = 0; i < EE; ++i) vx[i] = bqkv[2*EE + i];
        #pragma unroll
        for (int e = 0; e < EE; ++e) {
            const float tv = tokv[e];
            #pragma unroll
            for (int i = 0; i < EE; ++i)
                vx[i] = fmaf(tv, Wqkv[e*48 + 2*EE + i], vx[i]);
        }
        float4* vr = (float4*)(vb + bl*KVPAD + f*16);
        vr[0] = make_float4(vx[0],  vx[1],  vx[2],  vx[3]);
        vr[1] = make_float4(vx[4],  vx[5],  vx[6],  vx[7]);
        vr[2] = make_float4(vx[8],  vx[9],  vx[10], vx[11]);
        vr[3] = make_float4(vx[12], vx[13], vx[14], vx[15]);
    }

    // ---- scores vs all 16 k rows, scale 0.25
    float s[16];
    #pragma unroll
    for (int kk = 0; kk < 16; ++kk) {
        const float4* krow = (const float4*)(kb + bl*KVPAD + kk*16);
        float4 k0 = krow[0], k1 = krow[1], k2 = krow[2], k3 = krow[3];
        float d = q[0]*k0.x  + q[1]*k0.y  + q[2]*k0.z  + q[3]*k0.w
                + q[4]*k1.x  + q[5]*k1.y  + q[6]*k1.z  + q[7]*k1.w
                + q[8]*k2.x  + q[9]*k2.y  + q[10]*k2.z + q[11]*k2.w
                + q[12]*k3.x + q[13]*k3.y + q[14]*k3.z + q[15]*k3.w;
        s[kk] = d * 0.25f;
    }

    // ---- stable softmax
    float m = s[0];
    #pragma unroll
    for (int kk = 1; kk < 16; ++kk) m = fmaxf(m, s[kk]);
    float sum = 0.f;
    #pragma unroll
    for (int kk = 0; kk < 16; ++kk) { s[kk] = __expf(s[kk] - m); sum += s[kk]; }
    const float inv = 1.0f / sum;
    #pragma unroll
    for (int kk = 0; kk < 16; ++kk) s[kk] *= inv;

    // ---- column sums across 16 token-lanes -> 16*abar (replicated)
    #pragma unroll
    for (int kk = 0; kk < 16; ++kk) s[kk] = sum16(s[kk]);

    // ---- pooled_v[f]
    float pvf = 0.f;
    #pragma unroll
    for (int kk = 0; kk < 16; ++kk)
        pvf = fmaf(s[kk], vb[bl*KVPAD + kk*16 + f], pvf);
    pvf *= 0.0625f;

    // ---- wof[f] = Wo[f][:] . Wf
    float wof;
    {
        const float4* wr = (const float4*)(Wo + f*EE);
        float4 w0 = wr[0], w1 = wr[1], w2 = wr[2], w3 = wr[3];
        wof = w0.x*Wf[0]  + w0.y*Wf[1]  + w0.z*Wf[2]  + w0.w*Wf[3]
            + w1.x*Wf[4]  + w1.y*Wf[5]  + w1.z*Wf[6]  + w1.w*Wf[7]
            + w2.x*Wf[8]  + w2.y*Wf[9]  + w2.z*Wf[10] + w2.w*Wf[11]
            + w3.x*Wf[12] + w3.y*Wf[13] + w3.z*Wf[14] + w3.w*Wf[15];
    }

    float c = fmaf(pvf, wof, bo[f]*Wf[f]);
    c = sum16(c);

    if (f == 0) {
        float r = c + bf[0];
        out[gb] = (r >= 0.f) ? r : 0.01f*r;
    }
}

extern "C" void kernel_launch(void* const* d_in, const int* in_sizes, int n_in,
                              void* d_out, int out_size, void* d_ws, size_t ws_size,
                              hipStream_t stream)
{
    const float* x    = (const float*)d_in[0];
    const float* W1   = (const float*)d_in[1];
    const float* b1   = (const float*)d_in[2];
    const float* W2   = (const float*)d_in[3];
    const float* b2   = (const float*)d_in[4];
    const float* W3   = (const float*)d_in[5];
    const float* b3   = (const float*)d_in[6];
    const float* Wp   = (const float*)d_in[7];
    const float* bp   = (const float*)d_in[8];
    const float* Wqkv = (const float*)d_in[9];
    const float* bqkv = (const float*)d_in[10];
    const float* Wo   = (const float*)d_in[11];
    const float* bo   = (const float*)d_in[12];
    const float* Wf   = (const float*)d_in[13];
    const float* bf   = (const float*)d_in[14];
    float* out = (float*)d_out;

    // d_ws layout: [0,16MiB) tok bf16 [B][F][E]; at 16MiB: W3p fp32 (64KB) + bp3 (1KB)
    unsigned* tokb = (unsigned*)d_ws;
    float* w3p = (float*)((char*)d_ws + (16u << 20));
    float* bp3 = w3p + FF*HH*EE;

    w3p_kernel<<<FF, 256, 0, stream>>>(W3, b3, Wp, bp, w3p, bp3);
    spinn_subnet_kernel<<<dim3(BB/256 * FF), 256, 0, stream>>>(x, W1, b1, W2, b2, w3p, bp3, tokb);
    spinn_attn_kernel<<<BB/16, 256, 0, stream>>>(tokb, Wqkv, bqkv, Wo, bo, Wf, bf, out);
}